// Round 7
// baseline (4487.883 us; speedup 1.0000x reference)
//
#include <hip/hip_runtime.h>
#include <hip/hip_bf16.h>
#include <math.h>

#define B_     1024
#define VOCAB_ 130
#define EOS_   129

// Output FLOAT32 element offsets:
//   inv_features @0 (24576) | inv_class_emb @24576 (901120) | str_emb @925696
#define OUT_CLS_F  24576
#define OUT_STR_F  925696

// Workspace (float offsets): POOL 1024*32 | CNT 1024 | HC 1024*16 | T 2*128*48
#define OFF_POOL 0
#define OFF_CNT  32768
#define OFF_HC   33792
#define OFF_T    50176

// merged grid: 444 k2-role blocks first (220 fwd GRU + 220 bwd GRU + 4 classRNN),
// then 14960 k1-role blocks (backfill CUs around the long-running k2 blocks)
#define NK2   444
#define NK1   14960
#define NTOT  15404

typedef float f2 __attribute__((ext_vector_type(2)));

static __device__ const int d_MAP[19] =
    {128,93,41,91,61,34,40,37,33,63,43,47,36,42,96,48,95,46,128};

__device__ __forceinline__ float sigm_(float x){
    return __builtin_amdgcn_rcpf(1.f + __builtin_amdgcn_exp2f(-1.4426950408889634f * x));
}
__device__ __forceinline__ float tanh_(float x){
    return 2.f * __builtin_amdgcn_rcpf(1.f + __builtin_amdgcn_exp2f(-2.8853900817779268f * x)) - 1.f;
}
__device__ __forceinline__ int badf(float v) {
    return (v != v) || (fabsf(v) > 1e30f);
}
__device__ __forceinline__ f2 mkf2(float a, float b){ f2 r; r.x = a; r.y = b; return r; }

// ---------------- k0: precompute gi tables T[dir][c][j] = Wih_j . emb[c] + bih[j] (+bhh[j] for j<32)
__global__ void k0_tables(const float* __restrict__ emb,
                          const float* __restrict__ WihF, const float* __restrict__ bihF,
                          const float* __restrict__ bhhF,
                          const float* __restrict__ WihB, const float* __restrict__ bihB,
                          const float* __restrict__ bhhB, float* ws)
{
    int i = blockIdx.x * 256 + threadIdx.x;
    if (i >= 12288) return;                 // 2 * 128 * 48
    int dir = i / 6144, r = i - dir * 6144;
    int c = r / 48, j = r - c * 48;
    const float* Wih = dir ? WihB : WihF;
    const float* bih = dir ? bihB : bihF;
    const float* bhh = dir ? bhhB : bhhF;
    float v = bih[j] + ((j < 32) ? bhh[j] : 0.f);
    if (c != 0) {                           // padding_idx=0 -> emb row 0 is zero
        const float* e = emb + c * 16;
        #pragma unroll
        for (int d = 0; d < 16; ++d) v = fmaf(Wih[j * 16 + d], e[d], v);
    }
    ws[OFF_T + i] = v;
}

// ---------------- k12: merged embed-gather (k1 role) + GRU/RNN (k2 role)
// role: bi < 444 -> k2 (thread-per-sequence GRU / class RNN); else k1 (bi-444)
// LDS union (7184 floats = 28736 B):
//   GRU: [0,6400) T-table [128][50] | [6400,7168) Whh staged | [7168,7184) bhh_n
//   cls: [0,323) T2 [19][17]        | [336,592) rWhh staged
//   k1 : [0,2600) embF(pitch20)     | [2600,2920) chs
__global__ __launch_bounds__(256)
void k12_main(const int* oclass, const int* strs, const float* __restrict__ emb,
              const float* __restrict__ WhhF, const float* __restrict__ bhhF,
              const float* __restrict__ WhhB, const float* __restrict__ bhhB,
              const float* __restrict__ rWih, const float* __restrict__ rWhh,
              const float* __restrict__ rbih, const float* __restrict__ rbhh,
              float* ws, float* out)
{
    __shared__ __align__(16) float smem[7184];
    int bi0 = blockIdx.x, tid = threadIdx.x;

    if (bi0 >= NK2) {
        // ================= k1 role: f32 gathers (str_emb + EOS, inv_class_emb)
        int k1id = bi0 - NK2;
        float* embF = smem;                          // pitch 20
        int*   chs  = (int*)(smem + 2600);           // 4 * 80
        for (int i = tid; i < VOCAB_ * 16; i += 256) {
            int r = i >> 4, c = i & 15;
            embF[r * 20 + c] = (r == 0) ? 0.f : emb[i];   // padding_idx=0
        }
        __syncthreads();

        if (k1id < 14080) {
            int w = tid >> 6, lane = tid & 63;
            int s = k1id * 4 + w;
            const int* cp = strs + (long)s * 80;
            int ca = cp[lane];
            int cb = (lane < 16) ? cp[64 + lane] : 0;
            unsigned long long m1 = __ballot(ca != 0);
            unsigned long long m2 = __ballot((lane < 16) && (cb != 0));
            int L = __popcll(m1) + __popcll(m2);
            if (lane == L) ca = EOS_;
            if (lane < 16 && (64 + lane) == L) cb = EOS_;
            chs[w * 80 + lane] = ca;                 // wave-local slice: no barrier
            if (lane < 16) chs[w * 80 + 64 + lane] = cb;
            float4* dst = (float4*)(out + OUT_STR_F + (long)s * 1280);
            #pragma unroll
            for (int it = 0; it < 5; ++it) {
                int q = it * 64 + lane;
                int row = q >> 2, part = q & 3;
                int ch = chs[w * 80 + row];
                dst[q] = *(const float4*)&embF[ch * 20 + part * 4];
            }
        } else {
            int q = (k1id - 14080) * 256 + tid;
            int bs = q >> 2, part = q & 3;
            int c = d_MAP[oclass[bs]];
            float4* dst = (float4*)(out + OUT_CLS_F);
            dst[q] = *(const float4*)&embF[c * 20 + part * 4];
        }
        return;
    }

    // ================= k2 role
    int bi = bi0;

    if (bi < 440) {
        // ---- GRU: thread-per-sequence; h in registers, weights streamed
        //      from LDS as wave-uniform broadcast reads (no cross-lane ops)
        bool fwd = bi < 220;
        const float* __restrict__ Whh = fwd ? WhhF : WhhB;
        const float* __restrict__ bhh = fwd ? bhhF : bhhB;
        float* ldsT  = smem;                 // [128][50] gi-table
        float* ldsW  = smem + 6400;          // [768] Whh (r|z|n rows, natural order)
        float* ldsBn = smem + 7168;          // [16] bhh_n

        const float* Tg = ws + OFF_T + (fwd ? 0 : 6144);
        for (int i = tid; i < 6400; i += 256) {
            int c = i / 50, q = i - c * 50;
            if (q < 48) ldsT[i] = Tg[c * 48 + q];
        }
        for (int i = tid; i < 768; i += 256) ldsW[i] = Whh[i];
        if (tid < 16) ldsBn[tid] = bhh[32 + tid];
        __syncthreads();

        int s = (fwd ? bi : bi - 220) * 256 + tid;
        const int* cp = strs + (long)s * 80;

        // per-thread length via int4 loads (16B aligned: 320B rows)
        int L = 0;
        const int4* cp4 = (const int4*)cp;
        #pragma unroll
        for (int t = 0; t < 20; ++t) {
            int4 v = cp4[t];
            L += (v.x != 0) + (v.y != 0) + (v.z != 0) + (v.w != 0);
        }

        f2 h2[8];
        #pragma unroll
        for (int i = 0; i < 8; ++i) h2[i] = mkf2(0.f, 0.f);

        if (L > 0) {
            int base = fwd ? 0 : (L - 1);
            int stp  = fwd ? 1 : -1;
            int c = cp[base];
            for (int t = 0; t < L; ++t) {
                int cn = (t + 1 < L) ? cp[base + (t + 1) * stp] : 0;
                const float* Tr = ldsT + c * 50;
                float hn[16];
                #pragma unroll
                for (int j = 0; j < 16; ++j) {
                    const float* Wr = ldsW + j * 16;         // broadcast reads
                    const float* Wz = ldsW + 256 + j * 16;
                    const float* Wn = ldsW + 512 + j * 16;
                    f2 ar = mkf2(Tr[j], 0.f);
                    f2 az = mkf2(Tr[16 + j], 0.f);
                    f2 an = mkf2(ldsBn[j], 0.f);             // T_n stays out of an
                    #pragma unroll
                    for (int d2 = 0; d2 < 4; ++d2) {
                        float4 wr = *(const float4*)&Wr[d2 * 4];
                        float4 wz = *(const float4*)&Wz[d2 * 4];
                        float4 wn = *(const float4*)&Wn[d2 * 4];
                        f2 hA = h2[2 * d2], hB = h2[2 * d2 + 1];
                        ar = __builtin_elementwise_fma(mkf2(wr.x, wr.y), hA, ar);
                        az = __builtin_elementwise_fma(mkf2(wz.x, wz.y), hA, az);
                        an = __builtin_elementwise_fma(mkf2(wn.x, wn.y), hA, an);
                        ar = __builtin_elementwise_fma(mkf2(wr.z, wr.w), hB, ar);
                        az = __builtin_elementwise_fma(mkf2(wz.z, wz.w), hB, az);
                        an = __builtin_elementwise_fma(mkf2(wn.z, wn.w), hB, an);
                    }
                    float rg = sigm_(ar.x + ar.y);
                    float zg = sigm_(az.x + az.y);
                    float ng = tanh_(fmaf(rg, an.x + an.y, Tr[32 + j]));
                    float hold = (j & 1) ? h2[j >> 1].y : h2[j >> 1].x;
                    hn[j] = fmaf(zg, hold - ng, ng);         // (1-z)*n + z*h
                }
                #pragma unroll
                for (int i = 0; i < 8; ++i) h2[i] = mkf2(hn[2 * i], hn[2 * i + 1]);
                c = cn;
            }
            int b = s / 55;
            float* pool = ws + OFF_POOL + b * 32 + (fwd ? 0 : 16);
            #pragma unroll
            for (int i = 0; i < 8; ++i) {
                atomicAdd(&pool[2 * i],     h2[i].x);
                atomicAdd(&pool[2 * i + 1], h2[i].y);
            }
            if (fwd) atomicAdd(ws + OFF_CNT + b, 1.f);
        }
    } else {
        // ---- class RNN: thread-per-sample ----
        float* T2 = smem;                    // [19][17]
        float* rw = smem + 336;              // [256]
        for (int i = tid; i < 19 * 17; i += 256) {
            int o = i / 17, q = i - o * 17;
            if (q < 16) {
                int c = d_MAP[o];
                float v = rbih[q] + rbhh[q];
                #pragma unroll
                for (int d = 0; d < 16; ++d)
                    v = fmaf(rWih[q * 16 + d], emb[c * 16 + d], v);
                T2[i] = v;
            }
        }
        for (int i = tid; i < 256; i += 256) rw[i] = rWhh[i];
        __syncthreads();

        int smp = (bi - 440) * 256 + tid;
        const int* op = oclass + (long)smp * 55;
        int len = 0;
        #pragma unroll 11
        for (int t = 0; t < 55; ++t) len += (op[t] != 18);

        f2 h2[8];
        #pragma unroll
        for (int i = 0; i < 8; ++i) h2[i] = mkf2(0.f, 0.f);

        if (len > 0) {
            int o = op[0];
            for (int t = 0; t < len; ++t) {
                int on = (t + 1 < len) ? op[t + 1] : 0;
                float hn[16];
                #pragma unroll
                for (int j = 0; j < 16; ++j) {
                    const float* wj = rw + j * 16;
                    f2 a2 = mkf2(T2[o * 17 + j], 0.f);
                    #pragma unroll
                    for (int d2 = 0; d2 < 4; ++d2) {
                        float4 w = *(const float4*)&wj[d2 * 4];
                        a2 = __builtin_elementwise_fma(mkf2(w.x, w.y), h2[2 * d2], a2);
                        a2 = __builtin_elementwise_fma(mkf2(w.z, w.w), h2[2 * d2 + 1], a2);
                    }
                    hn[j] = tanh_(a2.x + a2.y);
                }
                #pragma unroll
                for (int i = 0; i < 8; ++i) h2[i] = mkf2(hn[2 * i], hn[2 * i + 1]);
                o = on;
            }
        }
        float* hc = ws + OFF_HC + smp * 16;
        #pragma unroll
        for (int i = 0; i < 8; ++i) {
            hc[2 * i]     = h2[i].x;
            hc[2 * i + 1] = h2[i].y;
        }
    }
}

// ---------------- k3: fusion MLP (f32 in/out), conditional diagnostic
__global__ void k3_fuse(const float* fW1, const float* fb1,
                        const float* fW2, const float* fb2,
                        float* ws, float* out)
{
    int b = blockIdx.x * 256 + threadIdx.x;
    if (b >= B_) return;
    float inv = 1.f / (ws[OFF_CNT + b] + 1e-8f);
    float comb[48];
    #pragma unroll
    for (int j = 0; j < 16; ++j) comb[j] = ws[OFF_HC + b * 16 + j];
    #pragma unroll
    for (int j = 0; j < 32; ++j) comb[16 + j] = ws[OFF_POOL + b * 32 + j] * inv;

    float hid[16];
    #pragma unroll
    for (int o = 0; o < 16; ++o) {
        float v = fb1[o];
        #pragma unroll
        for (int i = 0; i < 48; ++i) v = fmaf(fW1[o * 48 + i], comb[i], v);
        hid[o] = v > 0.f ? v : 0.f;
    }
    #pragma unroll
    for (int o = 0; o < 24; ++o) {
        float v = fb2[o];
        #pragma unroll
        for (int i = 0; i < 16; ++i) v = fmaf(fW2[o * 16 + i], hid[i], v);
        out[b * 24 + o] = v;
    }

    if (b == 0) {   // silent on success
        int bb = 0;
        if (!badf(ws[OFF_POOL]))    bb |= 1;
        if (!badf(ws[OFF_HC]))      bb |= 2;
        if (ws[OFF_CNT] > 0.5f)     bb |= 4;
        if (bb != 7) {
            float code = 16384.f + 128.f * (float)bb;
            #pragma unroll
            for (int i = 4; i < 12; ++i) out[i] = code;
        }
    }
}

// ------------------------------------------------------------------- launch
extern "C" void kernel_launch(void* const* d_in, const int* in_sizes, int n_in,
                              void* d_out, int out_size, void* d_ws, size_t ws_size,
                              hipStream_t stream)
{
    const int*   oclass = (const int*)d_in[0];
    const int*   strs   = (const int*)d_in[1];
    const float* emb    = (const float*)d_in[2];
    const float* rWih   = (const float*)d_in[3];
    const float* rWhh   = (const float*)d_in[4];
    const float* rbih   = (const float*)d_in[5];
    const float* rbhh   = (const float*)d_in[6];
    const float* gWihF  = (const float*)d_in[7];
    const float* gWhhF  = (const float*)d_in[8];
    const float* gbihF  = (const float*)d_in[9];
    const float* gbhhF  = (const float*)d_in[10];
    const float* gWihB  = (const float*)d_in[11];
    const float* gWhhB  = (const float*)d_in[12];
    const float* gbihB  = (const float*)d_in[13];
    const float* gbhhB  = (const float*)d_in[14];
    const float* fW1    = (const float*)d_in[15];
    const float* fb1    = (const float*)d_in[16];
    const float* fW2    = (const float*)d_in[17];
    const float* fb2    = (const float*)d_in[18];

    float* ws  = (float*)d_ws;
    float* out = (float*)d_out;

    hipMemsetAsync(d_ws, 0, 33792 * sizeof(float), stream);

    k0_tables<<<48, 256, 0, stream>>>(emb, gWihF, gbihF, gbhhF,
                                      gWihB, gbihB, gbhhB, ws);
    k12_main<<<NTOT, 256, 0, stream>>>(oclass, strs, emb,
                                       gWhhF, gbhhF, gWhhB, gbhhB,
                                       rWih, rWhh, rbih, rbhh, ws, out);
    k3_fuse<<<4, 256, 0, stream>>>(fW1, fb1, fW2, fb2, ws, out);
}

// Round 8
// 887.992 us; speedup vs baseline: 5.0540x; 5.0540x over previous
//
#include <hip/hip_runtime.h>
#include <hip/hip_bf16.h>
#include <math.h>

#define B_     1024
#define VOCAB_ 130
#define EOS_   129

// Output FLOAT32 element offsets:
//   inv_features @0 (24576) | inv_class_emb @24576 (901120) | str_emb @925696
#define OUT_CLS_F  24576
#define OUT_STR_F  925696

// Workspace (float offsets): POOL 1024*32 | CNT 1024 | HC 1024*16 | T 2*128*48
#define OFF_POOL 0
#define OFF_CNT  32768
#define OFF_HC   33792
#define OFF_T    50176

// merged grid: 444 k2-role blocks first (220 fwd GRU + 220 bwd GRU + 4 classRNN),
// then 14960 k1-role blocks (backfill CUs around the long-running k2 blocks)
#define NK2   444
#define NK1   14960
#define NTOT  15404

static __device__ const int d_MAP[19] =
    {128,93,41,91,61,34,40,37,33,63,43,47,36,42,96,48,95,46,128};

__device__ __forceinline__ float sigm_(float x){
    return __builtin_amdgcn_rcpf(1.f + __builtin_amdgcn_exp2f(-1.4426950408889634f * x));
}
__device__ __forceinline__ float tanh_(float x){
    return 2.f * __builtin_amdgcn_rcpf(1.f + __builtin_amdgcn_exp2f(-2.8853900817779268f * x)) - 1.f;
}
__device__ __forceinline__ int badf(float v) {
    return (v != v) || (fabsf(v) > 1e30f);
}

// 16-wide dot: acc += W[0..15] . h[0..15], W from LDS as 4x float4.
// Gate-serialized use (one DOT16 at a time) caps in-flight LDS data at 16 floats.
#define DOT16(acc, Wbase) { \
    const float4* W4_ = (const float4*)(Wbase); \
    float4 w0_ = W4_[0], w1_ = W4_[1], w2_ = W4_[2], w3_ = W4_[3]; \
    acc = fmaf(w0_.x, h[0],  acc); acc = fmaf(w0_.y, h[1],  acc); \
    acc = fmaf(w0_.z, h[2],  acc); acc = fmaf(w0_.w, h[3],  acc); \
    acc = fmaf(w1_.x, h[4],  acc); acc = fmaf(w1_.y, h[5],  acc); \
    acc = fmaf(w1_.z, h[6],  acc); acc = fmaf(w1_.w, h[7],  acc); \
    acc = fmaf(w2_.x, h[8],  acc); acc = fmaf(w2_.y, h[9],  acc); \
    acc = fmaf(w2_.z, h[10], acc); acc = fmaf(w2_.w, h[11], acc); \
    acc = fmaf(w3_.x, h[12], acc); acc = fmaf(w3_.y, h[13], acc); \
    acc = fmaf(w3_.z, h[14], acc); acc = fmaf(w3_.w, h[15], acc); }

// ---------------- k0: precompute gi tables T[dir][c][j] = Wih_j . emb[c] + bih[j] (+bhh[j] for j<32)
__global__ void k0_tables(const float* __restrict__ emb,
                          const float* __restrict__ WihF, const float* __restrict__ bihF,
                          const float* __restrict__ bhhF,
                          const float* __restrict__ WihB, const float* __restrict__ bihB,
                          const float* __restrict__ bhhB, float* ws)
{
    int i = blockIdx.x * 256 + threadIdx.x;
    if (i >= 12288) return;                 // 2 * 128 * 48
    int dir = i / 6144, r = i - dir * 6144;
    int c = r / 48, j = r - c * 48;
    const float* Wih = dir ? WihB : WihF;
    const float* bih = dir ? bihB : bihF;
    const float* bhh = dir ? bhhB : bhhF;
    float v = bih[j] + ((j < 32) ? bhh[j] : 0.f);
    if (c != 0) {                           // padding_idx=0 -> emb row 0 is zero
        const float* e = emb + c * 16;
        #pragma unroll
        for (int d = 0; d < 16; ++d) v = fmaf(Wih[j * 16 + d], e[d], v);
    }
    ws[OFF_T + i] = v;
}

// ---------------- k12: merged embed-gather (k1 role) + GRU/RNN (k2 role)
// role: bi < 444 -> k2 (thread-per-sequence GRU / class RNN); else k1 (bi-444)
// LDS union (7184 floats = 28736 B):
//   GRU: [0,6400) T-table [128][50] | [6400,7168) Whh staged | [7168,7184) bhh_n
//   cls: [0,323) T2 [19][17]        | [336,592) rWhh staged
//   k1 : [0,2600) embF(pitch20)     | [2600,2920) chs
// amdgpu_waves_per_eu(4,5): min-4 caps VGPR at 128 -- prevents the R7 spill
// (full-unroll software pipelining blew to 256 VGPR + 6.6 GB scratch traffic).
__global__ __launch_bounds__(256)
__attribute__((amdgpu_waves_per_eu(4, 5)))
void k12_main(const int* oclass, const int* strs, const float* __restrict__ emb,
              const float* __restrict__ WhhF, const float* __restrict__ bhhF,
              const float* __restrict__ WhhB, const float* __restrict__ bhhB,
              const float* __restrict__ rWih, const float* __restrict__ rWhh,
              const float* __restrict__ rbih, const float* __restrict__ rbhh,
              float* ws, float* out)
{
    __shared__ __align__(16) float smem[7184];
    int bi0 = blockIdx.x, tid = threadIdx.x;

    if (bi0 >= NK2) {
        // ================= k1 role: f32 gathers (str_emb + EOS, inv_class_emb)
        int k1id = bi0 - NK2;
        float* embF = smem;                          // pitch 20
        int*   chs  = (int*)(smem + 2600);           // 4 * 80
        for (int i = tid; i < VOCAB_ * 16; i += 256) {
            int r = i >> 4, c = i & 15;
            embF[r * 20 + c] = (r == 0) ? 0.f : emb[i];   // padding_idx=0
        }
        __syncthreads();

        if (k1id < 14080) {
            int w = tid >> 6, lane = tid & 63;
            int s = k1id * 4 + w;
            const int* cp = strs + (long)s * 80;
            int ca = cp[lane];
            int cb = (lane < 16) ? cp[64 + lane] : 0;
            unsigned long long m1 = __ballot(ca != 0);
            unsigned long long m2 = __ballot((lane < 16) && (cb != 0));
            int L = __popcll(m1) + __popcll(m2);
            if (lane == L) ca = EOS_;
            if (lane < 16 && (64 + lane) == L) cb = EOS_;
            chs[w * 80 + lane] = ca;                 // wave-local slice: no barrier
            if (lane < 16) chs[w * 80 + 64 + lane] = cb;
            float4* dst = (float4*)(out + OUT_STR_F + (long)s * 1280);
            #pragma unroll
            for (int it = 0; it < 5; ++it) {
                int q = it * 64 + lane;
                int row = q >> 2, part = q & 3;
                int ch = chs[w * 80 + row];
                dst[q] = *(const float4*)&embF[ch * 20 + part * 4];
            }
        } else {
            int q = (k1id - 14080) * 256 + tid;
            int bs = q >> 2, part = q & 3;
            int c = d_MAP[oclass[bs]];
            float4* dst = (float4*)(out + OUT_CLS_F);
            dst[q] = *(const float4*)&embF[c * 20 + part * 4];
        }
        return;
    }

    // ================= k2 role
    int bi = bi0;

    if (bi < 440) {
        // ---- GRU: thread-per-sequence; h in registers, weights streamed
        //      from LDS as wave-uniform broadcast reads (no cross-lane ops)
        bool fwd = bi < 220;
        const float* __restrict__ Whh = fwd ? WhhF : WhhB;
        const float* __restrict__ bhh = fwd ? bhhF : bhhB;
        float* ldsT  = smem;                 // [128][50] gi-table
        float* ldsW  = smem + 6400;          // [768] Whh (r|z|n rows)
        float* ldsBn = smem + 7168;          // [16] bhh_n

        const float* Tg = ws + OFF_T + (fwd ? 0 : 6144);
        for (int i = tid; i < 6400; i += 256) {
            int c = i / 50, q = i - c * 50;
            if (q < 48) ldsT[i] = Tg[c * 48 + q];
        }
        for (int i = tid; i < 768; i += 256) ldsW[i] = Whh[i];
        if (tid < 16) ldsBn[tid] = bhh[32 + tid];
        __syncthreads();

        int s = (fwd ? bi : bi - 220) * 256 + tid;
        const int* cp = strs + (long)s * 80;

        // per-thread length via int4 loads (16B aligned: 320B rows)
        int L = 0;
        const int4* cp4 = (const int4*)cp;
        #pragma unroll
        for (int t = 0; t < 20; ++t) {
            int4 v = cp4[t];
            L += (v.x != 0) + (v.y != 0) + (v.z != 0) + (v.w != 0);
        }

        float h[16];
        #pragma unroll
        for (int i = 0; i < 16; ++i) h[i] = 0.f;

        if (L > 0) {
            int base = fwd ? 0 : (L - 1);
            int stp  = fwd ? 1 : -1;
            int c  = cp[base];
            int c1 = (L > 1) ? cp[base + stp] : 0;
            for (int t = 0; t < L; ++t) {
                int c2 = (t + 2 < L) ? cp[base + (t + 2) * stp] : 0;
                const float* Tr = ldsT + c * 50;
                float hn[16];
                #pragma unroll
                for (int j = 0; j < 16; ++j) {
                    float ar = Tr[j];
                    DOT16(ar, ldsW + j * 16);
                    float az = Tr[16 + j];
                    DOT16(az, ldsW + 256 + j * 16);
                    float an = ldsBn[j];                 // T_n stays out of an
                    DOT16(an, ldsW + 512 + j * 16);
                    float rg = sigm_(ar);
                    float zg = sigm_(az);
                    float ng = tanh_(fmaf(rg, an, Tr[32 + j]));
                    hn[j] = fmaf(zg, h[j] - ng, ng);     // (1-z)*n + z*h
                    asm volatile("" ::: "memory");       // cap in-flight LDS loads
                }
                #pragma unroll
                for (int i = 0; i < 16; ++i) h[i] = hn[i];
                c = c1; c1 = c2;
            }
            int b = s / 55;
            float* pool = ws + OFF_POOL + b * 32 + (fwd ? 0 : 16);
            #pragma unroll
            for (int i = 0; i < 16; ++i) atomicAdd(&pool[i], h[i]);
            if (fwd) atomicAdd(ws + OFF_CNT + b, 1.f);
        }
    } else {
        // ---- class RNN: thread-per-sample ----
        float* T2 = smem;                    // [19][17]
        float* rw = smem + 336;              // [256]
        for (int i = tid; i < 19 * 17; i += 256) {
            int o = i / 17, q = i - o * 17;
            if (q < 16) {
                int c = d_MAP[o];
                float v = rbih[q] + rbhh[q];
                #pragma unroll
                for (int d = 0; d < 16; ++d)
                    v = fmaf(rWih[q * 16 + d], emb[c * 16 + d], v);
                T2[i] = v;
            }
        }
        for (int i = tid; i < 256; i += 256) rw[i] = rWhh[i];
        __syncthreads();

        int smp = (bi - 440) * 256 + tid;
        const int* op = oclass + (long)smp * 55;
        int len = 0;
        #pragma unroll 11
        for (int t = 0; t < 55; ++t) len += (op[t] != 18);

        float h[16];
        #pragma unroll
        for (int i = 0; i < 16; ++i) h[i] = 0.f;

        if (len > 0) {
            int o = op[0];
            for (int t = 0; t < len; ++t) {
                int on = (t + 1 < len) ? op[t + 1] : 0;
                float hn[16];
                #pragma unroll
                for (int j = 0; j < 16; ++j) {
                    float a = T2[o * 17 + j];
                    DOT16(a, rw + j * 16);
                    hn[j] = tanh_(a);
                    asm volatile("" ::: "memory");
                }
                #pragma unroll
                for (int i = 0; i < 16; ++i) h[i] = hn[i];
                o = on;
            }
        }
        float* hc = ws + OFF_HC + smp * 16;
        #pragma unroll
        for (int i = 0; i < 16; ++i) hc[i] = h[i];
    }
}

// ---------------- k3: fusion MLP (f32 in/out), conditional diagnostic
__global__ void k3_fuse(const float* fW1, const float* fb1,
                        const float* fW2, const float* fb2,
                        float* ws, float* out)
{
    int b = blockIdx.x * 256 + threadIdx.x;
    if (b >= B_) return;
    float inv = 1.f / (ws[OFF_CNT + b] + 1e-8f);
    float comb[48];
    #pragma unroll
    for (int j = 0; j < 16; ++j) comb[j] = ws[OFF_HC + b * 16 + j];
    #pragma unroll
    for (int j = 0; j < 32; ++j) comb[16 + j] = ws[OFF_POOL + b * 32 + j] * inv;

    float hid[16];
    #pragma unroll
    for (int o = 0; o < 16; ++o) {
        float v = fb1[o];
        #pragma unroll
        for (int i = 0; i < 48; ++i) v = fmaf(fW1[o * 48 + i], comb[i], v);
        hid[o] = v > 0.f ? v : 0.f;
    }
    #pragma unroll
    for (int o = 0; o < 24; ++o) {
        float v = fb2[o];
        #pragma unroll
        for (int i = 0; i < 16; ++i) v = fmaf(fW2[o * 16 + i], hid[i], v);
        out[b * 24 + o] = v;
    }

    if (b == 0) {   // silent on success
        int bb = 0;
        if (!badf(ws[OFF_POOL]))    bb |= 1;
        if (!badf(ws[OFF_HC]))      bb |= 2;
        if (ws[OFF_CNT] > 0.5f)     bb |= 4;
        if (bb != 7) {
            float code = 16384.f + 128.f * (float)bb;
            #pragma unroll
            for (int i = 4; i < 12; ++i) out[i] = code;
        }
    }
}

// ------------------------------------------------------------------- launch
extern "C" void kernel_launch(void* const* d_in, const int* in_sizes, int n_in,
                              void* d_out, int out_size, void* d_ws, size_t ws_size,
                              hipStream_t stream)
{
    const int*   oclass = (const int*)d_in[0];
    const int*   strs   = (const int*)d_in[1];
    const float* emb    = (const float*)d_in[2];
    const float* rWih   = (const float*)d_in[3];
    const float* rWhh   = (const float*)d_in[4];
    const float* rbih   = (const float*)d_in[5];
    const float* rbhh   = (const float*)d_in[6];
    const float* gWihF  = (const float*)d_in[7];
    const float* gWhhF  = (const float*)d_in[8];
    const float* gbihF  = (const float*)d_in[9];
    const float* gbhhF  = (const float*)d_in[10];
    const float* gWihB  = (const float*)d_in[11];
    const float* gWhhB  = (const float*)d_in[12];
    const float* gbihB  = (const float*)d_in[13];
    const float* gbhhB  = (const float*)d_in[14];
    const float* fW1    = (const float*)d_in[15];
    const float* fb1    = (const float*)d_in[16];
    const float* fW2    = (const float*)d_in[17];
    const float* fb2    = (const float*)d_in[18];

    float* ws  = (float*)d_ws;
    float* out = (float*)d_out;

    hipMemsetAsync(d_ws, 0, 33792 * sizeof(float), stream);

    k0_tables<<<48, 256, 0, stream>>>(emb, gWihF, gbihF, gbhhF,
                                      gWihB, gbihB, gbhhB, ws);
    k12_main<<<NTOT, 256, 0, stream>>>(oclass, strs, emb,
                                       gWhhF, gbhhF, gWhhB, gbhhB,
                                       rWih, rWhh, rbih, rbhh, ws, out);
    k3_fuse<<<4, 256, 0, stream>>>(fW1, fb1, fW2, fb2, ws, out);
}

// Round 9
// 860.129 us; speedup vs baseline: 5.2177x; 1.0324x over previous
//
#include <hip/hip_runtime.h>
#include <hip/hip_bf16.h>
#include <math.h>

#define B_     1024
#define VOCAB_ 130
#define EOS_   129

// Output FLOAT32 element offsets:
//   inv_features @0 (24576) | inv_class_emb @24576 (901120) | str_emb @925696
#define OUT_CLS_F  24576
#define OUT_STR_F  925696

// Workspace (float offsets): POOL 1024*32 | CNT 1024 | HC 1024*16 | T 2*128*48
#define OFF_POOL 0
#define OFF_CNT  32768
#define OFF_HC   33792
#define OFF_T    50176

// merged grid: 444 k2-role blocks first (220 fwd GRU + 220 bwd GRU + 4 classRNN),
// then 14960 k1-role blocks (backfill CUs around the long-running k2 blocks)
#define NK2   444
#define NK1   14960
#define NTOT  15404

static __device__ const int d_MAP[19] =
    {128,93,41,91,61,34,40,37,33,63,43,47,36,42,96,48,95,46,128};

__device__ __forceinline__ float sigm_(float x){
    return __builtin_amdgcn_rcpf(1.f + __builtin_amdgcn_exp2f(-1.4426950408889634f * x));
}
__device__ __forceinline__ float tanh_(float x){
    return 2.f * __builtin_amdgcn_rcpf(1.f + __builtin_amdgcn_exp2f(-2.8853900817779268f * x)) - 1.f;
}
__device__ __forceinline__ int badf(float v) {
    return (v != v) || (fabsf(v) > 1e30f);
}

// 16-wide dot from LDS (wave-uniform broadcast rows), h in registers.
#define DOT16(acc, Wbase) { \
    const float4* W4_ = (const float4*)(Wbase); \
    float4 w0_ = W4_[0], w1_ = W4_[1], w2_ = W4_[2], w3_ = W4_[3]; \
    acc = fmaf(w0_.x, h[0],  acc); acc = fmaf(w0_.y, h[1],  acc); \
    acc = fmaf(w0_.z, h[2],  acc); acc = fmaf(w0_.w, h[3],  acc); \
    acc = fmaf(w1_.x, h[4],  acc); acc = fmaf(w1_.y, h[5],  acc); \
    acc = fmaf(w1_.z, h[6],  acc); acc = fmaf(w1_.w, h[7],  acc); \
    acc = fmaf(w2_.x, h[8],  acc); acc = fmaf(w2_.y, h[9],  acc); \
    acc = fmaf(w2_.z, h[10], acc); acc = fmaf(w2_.w, h[11], acc); \
    acc = fmaf(w3_.x, h[12], acc); acc = fmaf(w3_.y, h[13], acc); \
    acc = fmaf(w3_.z, h[14], acc); acc = fmaf(w3_.w, h[15], acc); }

// ---------------- k0: precompute gi tables T[dir][c][j] = Wih_j . emb[c] + bih[j] (+bhh[j] for j<32)
__global__ void k0_tables(const float* __restrict__ emb,
                          const float* __restrict__ WihF, const float* __restrict__ bihF,
                          const float* __restrict__ bhhF,
                          const float* __restrict__ WihB, const float* __restrict__ bihB,
                          const float* __restrict__ bhhB, float* ws)
{
    int i = blockIdx.x * 256 + threadIdx.x;
    if (i >= 12288) return;                 // 2 * 128 * 48
    int dir = i / 6144, r = i - dir * 6144;
    int c = r / 48, j = r - c * 48;
    const float* Wih = dir ? WihB : WihF;
    const float* bih = dir ? bihB : bihF;
    const float* bhh = dir ? bhhB : bhhF;
    float v = bih[j] + ((j < 32) ? bhh[j] : 0.f);
    if (c != 0) {                           // padding_idx=0 -> emb row 0 is zero
        const float* e = emb + c * 16;
        #pragma unroll
        for (int d = 0; d < 16; ++d) v = fmaf(Wih[j * 16 + d], e[d], v);
    }
    ws[OFF_T + i] = v;
}

// ---------------- k12: merged embed-gather (k1 role) + GRU/RNN (k2 role)
// role: bi < 444 -> k2 (thread-per-sequence GRU / class RNN); else k1 (bi-444)
// LDS union (7312 floats = 29248 B):
//   GRU: [0,6528) T-table [128][51] | [6528,7296) Whh | [7296,7312) bhh_n
//   cls: [0,323) T2 [19][17]        | [336,592) rWhh
//   k1 : [0,2600) embF(pitch20)     | [2600,2920) chs
// waves_per_eu(3,4): 170-VGPR cap -- room to pipeline 2 j-iterations of
// broadcast weight loads, hard ceiling against the R7 full-unroll spill.
__global__ __launch_bounds__(256)
__attribute__((amdgpu_waves_per_eu(3, 4)))
void k12_main(const int* oclass, const int* strs, const float* __restrict__ emb,
              const float* __restrict__ WhhF, const float* __restrict__ bhhF,
              const float* __restrict__ WhhB, const float* __restrict__ bhhB,
              const float* __restrict__ rWih, const float* __restrict__ rWhh,
              const float* __restrict__ rbih, const float* __restrict__ rbhh,
              float* ws, float* out)
{
    __shared__ __align__(16) float smem[7312];
    int bi0 = blockIdx.x, tid = threadIdx.x;

    if (bi0 >= NK2) {
        // ================= k1 role: f32 gathers (str_emb + EOS, inv_class_emb)
        int k1id = bi0 - NK2;
        float* embF = smem;                          // pitch 20
        int*   chs  = (int*)(smem + 2600);           // 4 * 80
        for (int i = tid; i < VOCAB_ * 16; i += 256) {
            int r = i >> 4, c = i & 15;
            embF[r * 20 + c] = (r == 0) ? 0.f : emb[i];   // padding_idx=0
        }
        __syncthreads();

        if (k1id < 14080) {
            int w = tid >> 6, lane = tid & 63;
            int s = k1id * 4 + w;
            const int* cp = strs + (long)s * 80;
            int ca = cp[lane];
            int cb = (lane < 16) ? cp[64 + lane] : 0;
            unsigned long long m1 = __ballot(ca != 0);
            unsigned long long m2 = __ballot((lane < 16) && (cb != 0));
            int L = __popcll(m1) + __popcll(m2);
            if (lane == L) ca = EOS_;
            if (lane < 16 && (64 + lane) == L) cb = EOS_;
            chs[w * 80 + lane] = ca;                 // wave-local slice: no barrier
            if (lane < 16) chs[w * 80 + 64 + lane] = cb;
            float4* dst = (float4*)(out + OUT_STR_F + (long)s * 1280);
            #pragma unroll
            for (int it = 0; it < 5; ++it) {
                int q = it * 64 + lane;
                int row = q >> 2, part = q & 3;
                int ch = chs[w * 80 + row];
                dst[q] = *(const float4*)&embF[ch * 20 + part * 4];
            }
        } else {
            int q = (k1id - 14080) * 256 + tid;
            int bs = q >> 2, part = q & 3;
            int c = d_MAP[oclass[bs]];
            float4* dst = (float4*)(out + OUT_CLS_F);
            dst[q] = *(const float4*)&embF[c * 20 + part * 4];
        }
        return;
    }

    // ================= k2 role
    int bi = bi0;

    if (bi < 440) {
        // ---- GRU: thread-per-sequence; h in registers, weights broadcast
        //      from LDS (wave-uniform), T-rows lane-varying at odd pitch 51
        bool fwd = bi < 220;
        const float* __restrict__ Whh = fwd ? WhhF : WhhB;
        const float* __restrict__ bhh = fwd ? bhhF : bhhB;
        float* ldsT  = smem;                 // [128][51] gi-table
        float* ldsW  = smem + 6528;          // [768] Whh (r|z|n rows)
        float* ldsBn = smem + 7296;          // [16] bhh_n

        const float* Tg = ws + OFF_T + (fwd ? 0 : 6144);
        for (int i = tid; i < 6528; i += 256) {
            int c = i / 51, q = i - c * 51;
            if (q < 48) ldsT[i] = Tg[c * 48 + q];
        }
        for (int i = tid; i < 768; i += 256) ldsW[i] = Whh[i];
        if (tid < 16) ldsBn[tid] = bhh[32 + tid];
        __syncthreads();

        int s = (fwd ? bi : bi - 220) * 256 + tid;
        const int* cp = strs + (long)s * 80;

        // per-thread length via int4 loads (16B aligned: 320B rows)
        int L = 0;
        const int4* cp4 = (const int4*)cp;
        #pragma unroll
        for (int t = 0; t < 20; ++t) {
            int4 v = cp4[t];
            L += (v.x != 0) + (v.y != 0) + (v.z != 0) + (v.w != 0);
        }

        float h[16];
        #pragma unroll
        for (int i = 0; i < 16; ++i) h[i] = 0.f;

        if (L > 0) {
            int base = fwd ? 0 : (L - 1);
            int stp  = fwd ? 1 : -1;
            int c  = cp[base];
            int c1 = (L > 1) ? cp[base + stp] : 0;
            for (int t = 0; t < L; ++t) {
                int c2 = (t + 2 < L) ? cp[base + (t + 2) * stp] : 0;
                const float* Tr = ldsT + c * 51;
                float hn[16];
                #pragma unroll 2
                for (int j = 0; j < 16; ++j) {
                    float tr = Tr[j];            // issue early; folded after dot
                    float tz = Tr[16 + j];
                    float tn = Tr[32 + j];
                    float bn = ldsBn[j];
                    float ar = 0.f, az = 0.f, an = 0.f;
                    DOT16(ar, ldsW + j * 16);
                    DOT16(az, ldsW + 256 + j * 16);
                    DOT16(an, ldsW + 512 + j * 16);
                    float rg = sigm_(ar + tr);
                    float zg = sigm_(az + tz);
                    float ng = tanh_(fmaf(rg, an + bn, tn));  // T_n outside r*()
                    hn[j] = fmaf(zg, h[j] - ng, ng);          // (1-z)*n + z*h
                }
                #pragma unroll
                for (int i = 0; i < 16; ++i) h[i] = hn[i];
                c = c1; c1 = c2;
            }
            int b = s / 55;
            float* pool = ws + OFF_POOL + b * 32 + (fwd ? 0 : 16);
            #pragma unroll
            for (int i = 0; i < 16; ++i) atomicAdd(&pool[i], h[i]);
            if (fwd) atomicAdd(ws + OFF_CNT + b, 1.f);
        }
    } else {
        // ---- class RNN: thread-per-sample ----
        float* T2 = smem;                    // [19][17]
        float* rw = smem + 336;              // [256]
        for (int i = tid; i < 19 * 17; i += 256) {
            int o = i / 17, q = i - o * 17;
            if (q < 16) {
                int c = d_MAP[o];
                float v = rbih[q] + rbhh[q];
                #pragma unroll
                for (int d = 0; d < 16; ++d)
                    v = fmaf(rWih[q * 16 + d], emb[c * 16 + d], v);
                T2[i] = v;
            }
        }
        for (int i = tid; i < 256; i += 256) rw[i] = rWhh[i];
        __syncthreads();

        int smp = (bi - 440) * 256 + tid;
        const int* op = oclass + (long)smp * 55;
        int len = 0;
        #pragma unroll 11
        for (int t = 0; t < 55; ++t) len += (op[t] != 18);

        float h[16];
        #pragma unroll
        for (int i = 0; i < 16; ++i) h[i] = 0.f;

        if (len > 0) {
            int o = op[0];
            for (int t = 0; t < len; ++t) {
                int on = (t + 1 < len) ? op[t + 1] : 0;
                float hn[16];
                #pragma unroll 2
                for (int j = 0; j < 16; ++j) {
                    float a = T2[o * 17 + j];
                    DOT16(a, rw + j * 16);
                    hn[j] = tanh_(a);
                }
                #pragma unroll
                for (int i = 0; i < 16; ++i) h[i] = hn[i];
                o = on;
            }
        }
        float* hc = ws + OFF_HC + smp * 16;
        #pragma unroll
        for (int i = 0; i < 16; ++i) hc[i] = h[i];
    }
}

// ---------------- k3: fusion MLP (f32 in/out), conditional diagnostic
__global__ void k3_fuse(const float* fW1, const float* fb1,
                        const float* fW2, const float* fb2,
                        float* ws, float* out)
{
    int b = blockIdx.x * 256 + threadIdx.x;
    if (b >= B_) return;
    float inv = 1.f / (ws[OFF_CNT + b] + 1e-8f);
    float comb[48];
    #pragma unroll
    for (int j = 0; j < 16; ++j) comb[j] = ws[OFF_HC + b * 16 + j];
    #pragma unroll
    for (int j = 0; j < 32; ++j) comb[16 + j] = ws[OFF_POOL + b * 32 + j] * inv;

    float hid[16];
    #pragma unroll
    for (int o = 0; o < 16; ++o) {
        float v = fb1[o];
        #pragma unroll
        for (int i = 0; i < 48; ++i) v = fmaf(fW1[o * 48 + i], comb[i], v);
        hid[o] = v > 0.f ? v : 0.f;
    }
    #pragma unroll
    for (int o = 0; o < 24; ++o) {
        float v = fb2[o];
        #pragma unroll
        for (int i = 0; i < 16; ++i) v = fmaf(fW2[o * 16 + i], hid[i], v);
        out[b * 24 + o] = v;
    }

    if (b == 0) {   // silent on success
        int bb = 0;
        if (!badf(ws[OFF_POOL]))    bb |= 1;
        if (!badf(ws[OFF_HC]))      bb |= 2;
        if (ws[OFF_CNT] > 0.5f)     bb |= 4;
        if (bb != 7) {
            float code = 16384.f + 128.f * (float)bb;
            #pragma unroll
            for (int i = 4; i < 12; ++i) out[i] = code;
        }
    }
}

// ------------------------------------------------------------------- launch
extern "C" void kernel_launch(void* const* d_in, const int* in_sizes, int n_in,
                              void* d_out, int out_size, void* d_ws, size_t ws_size,
                              hipStream_t stream)
{
    const int*   oclass = (const int*)d_in[0];
    const int*   strs   = (const int*)d_in[1];
    const float* emb    = (const float*)d_in[2];
    const float* rWih   = (const float*)d_in[3];
    const float* rWhh   = (const float*)d_in[4];
    const float* rbih   = (const float*)d_in[5];
    const float* rbhh   = (const float*)d_in[6];
    const float* gWihF  = (const float*)d_in[7];
    const float* gWhhF  = (const float*)d_in[8];
    const float* gbihF  = (const float*)d_in[9];
    const float* gbhhF  = (const float*)d_in[10];
    const float* gWihB  = (const float*)d_in[11];
    const float* gWhhB  = (const float*)d_in[12];
    const float* gbihB  = (const float*)d_in[13];
    const float* gbhhB  = (const float*)d_in[14];
    const float* fW1    = (const float*)d_in[15];
    const float* fb1    = (const float*)d_in[16];
    const float* fW2    = (const float*)d_in[17];
    const float* fb2    = (const float*)d_in[18];

    float* ws  = (float*)d_ws;
    float* out = (float*)d_out;

    hipMemsetAsync(d_ws, 0, 33792 * sizeof(float), stream);

    k0_tables<<<48, 256, 0, stream>>>(emb, gWihF, gbihF, gbhhF,
                                      gWihB, gbihB, gbhhB, ws);
    k12_main<<<NTOT, 256, 0, stream>>>(oclass, strs, emb,
                                       gWhhF, gbhhF, gWhhB, gbhhB,
                                       rWih, rWhh, rbih, rbhh, ws, out);
    k3_fuse<<<4, 256, 0, stream>>>(fW1, fb1, fW2, fb2, ws, out);
}

// Round 11
// 691.475 us; speedup vs baseline: 6.4903x; 1.2439x over previous
//
#include <hip/hip_runtime.h>
#include <hip/hip_bf16.h>
#include <math.h>

#define B_     1024
#define VOCAB_ 130
#define EOS_   129

// Output FLOAT32 element offsets:
//   inv_features @0 (24576) | inv_class_emb @24576 (901120) | str_emb @925696
#define OUT_CLS_F  24576
#define OUT_STR_F  925696

// Workspace (float offsets): POOL 1024*32 | CNT 1024 | HC 1024*16 | T 2*128*48
#define OFF_POOL 0
#define OFF_CNT  32768
#define OFF_HC   33792
#define OFF_T    50176

// merged grid: 3524 k2-role (1760 fwd GRU + 1760 bwd GRU + 4 classRNN)
// interleaved 1:4 with 14960 k1-role
#define NK2   3524
#define NK1   14960
#define NINT  17620            // 5 * NK2 interleaved prefix
#define NTOT  18484

static __device__ const int d_MAP[19] =
    {128,93,41,91,61,34,40,37,33,63,43,47,36,42,96,48,95,46,128};

__device__ __forceinline__ float sigm_(float x){
    return __builtin_amdgcn_rcpf(1.f + __builtin_amdgcn_exp2f(-1.4426950408889634f * x));
}
__device__ __forceinline__ float tanh_(float x){
    return 2.f * __builtin_amdgcn_rcpf(1.f + __builtin_amdgcn_exp2f(-2.8853900817779268f * x)) - 1.f;
}
__device__ __forceinline__ int badf(float v) {
    return (v != v) || (fabsf(v) > 1e30f);
}

// group-of-16 integer reduce: xor 1,2,4,8 (literal swizzle patterns)
#define RED16(x) \
    x += __builtin_amdgcn_ds_swizzle(x, 0x041F); \
    x += __builtin_amdgcn_ds_swizzle(x, 0x081F); \
    x += __builtin_amdgcn_ds_swizzle(x, 0x101F); \
    x += __builtin_amdgcn_ds_swizzle(x, 0x201F);

// acc += sum_d w[d]*h[d] over 16, given 4+4 float4s
#define FMA16(acc, w0,w1,w2,w3, x0,x1,x2,x3) \
    acc = fmaf(w0.x,x0.x,acc); acc = fmaf(w0.y,x0.y,acc); \
    acc = fmaf(w0.z,x0.z,acc); acc = fmaf(w0.w,x0.w,acc); \
    acc = fmaf(w1.x,x1.x,acc); acc = fmaf(w1.y,x1.y,acc); \
    acc = fmaf(w1.z,x1.z,acc); acc = fmaf(w1.w,x1.w,acc); \
    acc = fmaf(w2.x,x2.x,acc); acc = fmaf(w2.y,x2.y,acc); \
    acc = fmaf(w2.z,x2.z,acc); acc = fmaf(w2.w,x2.w,acc); \
    acc = fmaf(w3.x,x3.x,acc); acc = fmaf(w3.y,x3.y,acc); \
    acc = fmaf(w3.z,x3.z,acc); acc = fmaf(w3.w,x3.w,acc);

// ---------------- k0: precompute gi tables T[dir][c][j] = Wih_j . emb[c] + bih[j] (+bhh[j] for j<32)
__global__ void k0_tables(const float* __restrict__ emb,
                          const float* __restrict__ WihF, const float* __restrict__ bihF,
                          const float* __restrict__ bhhF,
                          const float* __restrict__ WihB, const float* __restrict__ bihB,
                          const float* __restrict__ bhhB, float* ws)
{
    int i = blockIdx.x * 256 + threadIdx.x;
    if (i >= 12288) return;                 // 2 * 128 * 48
    int dir = i / 6144, r = i - dir * 6144;
    int c = r / 48, j = r - c * 48;
    const float* Wih = dir ? WihB : WihF;
    const float* bih = dir ? bihB : bihF;
    const float* bhh = dir ? bhhB : bhhF;
    float v = bih[j] + ((j < 32) ? bhh[j] : 0.f);
    if (c != 0) {                           // padding_idx=0 -> emb row 0 is zero
        const float* e = emb + c * 16;
        #pragma unroll
        for (int d = 0; d < 16; ++d) v = fmaf(Wih[j * 16 + d], e[d], v);
    }
    ws[OFF_T + i] = v;
}

// ---------------- k12: merged embed-gather (k1 role) + GRU/RNN (k2 role)
// role: bi<17620: bi%5==0 -> k2(bi/5), else k1(bi - bi/5 - 1);
//       bi>=17620 -> k1(14096 + bi - 17620)
// LDS union (7760 floats = 31040 B):
//   GRU: [0,6272) T[128][49] | [6272,7232) W[48][20] | [7232,7744) hb | [7744,7760) bn
//   cls: [0,323) T2[19][17]  | [336,592) rWhh
//   k1 : [0,2600) embF(pitch20) | [2600,2920) chs
__global__ __launch_bounds__(256)
__attribute__((amdgpu_waves_per_eu(3, 4)))
void k12_main(const int* oclass, const int* strs, const float* __restrict__ emb,
              const float* __restrict__ WhhF, const float* __restrict__ bhhF,
              const float* __restrict__ WhhB, const float* __restrict__ bhhB,
              const float* __restrict__ rWih, const float* __restrict__ rWhh,
              const float* __restrict__ rbih, const float* __restrict__ rbhh,
              float* ws, float* out)
{
    __shared__ __align__(16) float smem[7760];
    int bi0 = blockIdx.x, tid = threadIdx.x;

    int k2id = -1, k1id;
    if (bi0 < NINT) {
        if (bi0 % 5 == 0) k2id = bi0 / 5;
        else              k1id = bi0 - bi0 / 5 - 1;
    } else {
        k1id = 14096 + (bi0 - NINT);
    }

    if (k2id < 0) {
        // ================= k1 role: f32 gathers (str_emb + EOS, inv_class_emb)
        float* embF = smem;                          // pitch 20
        int*   chs  = (int*)(smem + 2600);           // 4 * 80
        for (int i = tid; i < VOCAB_ * 16; i += 256) {
            int r = i >> 4, c = i & 15;
            embF[r * 20 + c] = (r == 0) ? 0.f : emb[i];   // padding_idx=0
        }
        __syncthreads();

        if (k1id < 14080) {
            int w = tid >> 6, lane = tid & 63;
            int s = k1id * 4 + w;
            const int* cp = strs + (long)s * 80;
            int ca = cp[lane];
            int cb = (lane < 16) ? cp[64 + lane] : 0;
            unsigned long long m1 = __ballot(ca != 0);
            unsigned long long m2 = __ballot((lane < 16) && (cb != 0));
            int L = __popcll(m1) + __popcll(m2);
            if (lane == L) ca = EOS_;
            if (lane < 16 && (64 + lane) == L) cb = EOS_;
            chs[w * 80 + lane] = ca;                 // wave-local slice: no barrier
            if (lane < 16) chs[w * 80 + 64 + lane] = cb;
            float4* dst = (float4*)(out + OUT_STR_F + (long)s * 1280);
            #pragma unroll
            for (int it = 0; it < 5; ++it) {
                int q = it * 64 + lane;
                int row = q >> 2, part = q & 3;
                int ch = chs[w * 80 + row];
                dst[q] = *(const float4*)&embF[ch * 20 + part * 4];
            }
        } else {
            int q = (k1id - 14080) * 256 + tid;
            int bs = q >> 2, part = q & 3;
            int c = d_MAP[oclass[bs]];
            float4* dst = (float4*)(out + OUT_CLS_F);
            dst[q] = *(const float4*)&embF[c * 20 + part * 4];
        }
        return;
    }

    // ================= k2 role
    int bi = k2id;
    int grp = tid >> 4, j = tid & 15;

    if (bi < 3520) {
        // ---- GRU: 16 lanes per group, 2 sequences per group.
        //      h in LDS hb (R3-proven exchange); weights re-read from LDS each
        //      step as short-lived b128s -> no long-lived regs, no AGPR parking.
        bool fwd = bi < 1760;
        const float* __restrict__ Whh = fwd ? WhhF : WhhB;
        const float* __restrict__ bhh = fwd ? bhhF : bhhB;
        float* ldsT  = smem;                 // [128][49]
        float* ldsW  = smem + 6272;          // [48][20]
        float* ldsHB = smem + 7232;          // [16][32]
        float* ldsBn = smem + 7744;          // [16]

        const float* Tg = ws + OFF_T + (fwd ? 0 : 6144);
        for (int i = tid; i < 6144; i += 256) {
            int c = i / 48, q = i - c * 48;
            ldsT[c * 49 + q] = Tg[i];
        }
        for (int i = tid; i < 768; i += 256) {
            int r = i >> 4, d = i & 15;
            ldsW[r * 20 + d] = Whh[i];
        }
        if (tid < 16) ldsBn[tid] = bhh[32 + tid];
        __syncthreads();

        float* hbA = ldsHB + grp * 32;
        float* hbB = hbA + 16;
        int sA = (fwd ? bi : bi - 1760) * 32 + grp * 2;
        int sB = sA + 1;
        const int* cpA = strs + (long)sA * 80;
        const int* cpB = strs + (long)sB * 80;

        // group-parallel lengths (both seqs), swizzle-reduce xor 1,2,4,8
        int la = 0, lb = 0;
        #pragma unroll
        for (int k = 0; k < 5; ++k) {
            la += (cpA[j + 16 * k] != 0);
            lb += (cpB[j + 16 * k] != 0);
        }
        RED16(la)
        RED16(lb)
        int LA = la, LB = lb;
        int Lmax = (LA > LB) ? LA : LB;

        float bnj = ldsBn[j];
        float hA = 0.f, hB = 0.f;
        hbA[j] = 0.f; hbB[j] = 0.f;
        __builtin_amdgcn_wave_barrier();

        if (Lmax > 0) {
            int lamx = (LA > 0) ? LA - 1 : 0;
            int lbmx = (LB > 0) ? LB - 1 : 0;
            int baseA = fwd ? 0 : lamx;
            int baseB = fwd ? 0 : lbmx;
            int stp = fwd ? 1 : -1;
            int cA = cpA[baseA];
            int cB = cpB[baseB];
            int wofs = 0;
            for (int t = 0; t < Lmax; ++t) {
                // next-char prefetch, clamped into valid range
                int tA1 = t + 1; if (tA1 > lamx) tA1 = lamx;
                int tB1 = t + 1; if (tB1 > lbmx) tB1 = lbmx;
                int cAn = cpA[baseA + tA1 * stp];
                int cBn = cpB[baseB + tB1 * stp];

                // launder weight base: loads stay in-loop, live one iteration
                asm volatile("" : "+v"(wofs));
                const float4* W4 = (const float4*)ldsW + wofs;

                const float* TrA = ldsT + cA * 49;
                const float* TrB = ldsT + cB * 49;
                float trA = TrA[j], tzA = TrA[16 + j], tnA = TrA[32 + j];
                float trB = TrB[j], tzB = TrB[16 + j], tnB = TrB[32 + j];

                float4 r0 = W4[j*5],      r1 = W4[j*5+1],      r2 = W4[j*5+2],      r3 = W4[j*5+3];
                float4 z0 = W4[(16+j)*5], z1 = W4[(16+j)*5+1], z2 = W4[(16+j)*5+2], z3 = W4[(16+j)*5+3];
                float4 n0 = W4[(32+j)*5], n1 = W4[(32+j)*5+1], n2 = W4[(32+j)*5+2], n3 = W4[(32+j)*5+3];

                float4 a0 = *(const float4*)&hbA[0],  a1 = *(const float4*)&hbA[4];
                float4 a2 = *(const float4*)&hbA[8],  a3 = *(const float4*)&hbA[12];
                float4 b0 = *(const float4*)&hbB[0],  b1 = *(const float4*)&hbB[4];
                float4 b2 = *(const float4*)&hbB[8],  b3 = *(const float4*)&hbB[12];

                float arA = trA, azA = tzA, anA = bnj;
                float arB = trB, azB = tzB, anB = bnj;
                FMA16(arA, r0,r1,r2,r3, a0,a1,a2,a3);
                FMA16(arB, r0,r1,r2,r3, b0,b1,b2,b3);
                FMA16(azA, z0,z1,z2,z3, a0,a1,a2,a3);
                FMA16(azB, z0,z1,z2,z3, b0,b1,b2,b3);
                FMA16(anA, n0,n1,n2,n3, a0,a1,a2,a3);
                FMA16(anB, n0,n1,n2,n3, b0,b1,b2,b3);

                float rgA = sigm_(arA), rgB = sigm_(arB);
                float zgA = sigm_(azA), zgB = sigm_(azB);
                float ngA = tanh_(fmaf(rgA, anA, tnA));   // T_n outside r*()
                float ngB = tanh_(fmaf(rgB, anB, tnB));
                float hAn = fmaf(zgA, hA - ngA, ngA);
                float hBn = fmaf(zgB, hB - ngB, ngB);
                hA = (t < LA) ? hAn : hA;                 // predicated update
                hB = (t < LB) ? hBn : hB;
                hbA[j] = hA; hbB[j] = hB;
                __builtin_amdgcn_wave_barrier();
                cA = cAn; cB = cBn;
            }
            if (LA > 0) {
                int bA = sA / 55;
                atomicAdd(ws + OFF_POOL + bA * 32 + (fwd ? 0 : 16) + j, hA);
                if (fwd && j == 0) atomicAdd(ws + OFF_CNT + bA, 1.f);
            }
            if (LB > 0) {
                int bB = sB / 55;
                atomicAdd(ws + OFF_POOL + bB * 32 + (fwd ? 0 : 16) + j, hB);
                if (fwd && j == 0) atomicAdd(ws + OFF_CNT + bB, 1.f);
            }
        }
    } else {
        // ---- class RNN: thread-per-sample (R9-proven) ----
        float* T2 = smem;                    // [19][17]
        float* rw = smem + 336;              // [256]
        for (int i = tid; i < 19 * 17; i += 256) {
            int o = i / 17, q = i - o * 17;
            if (q < 16) {
                int c = d_MAP[o];
                float v = rbih[q] + rbhh[q];
                #pragma unroll
                for (int d = 0; d < 16; ++d)
                    v = fmaf(rWih[q * 16 + d], emb[c * 16 + d], v);
                T2[i] = v;
            }
        }
        for (int i = tid; i < 256; i += 256) rw[i] = rWhh[i];
        __syncthreads();

        int smp = (bi - 3520) * 256 + tid;
        const int* op = oclass + (long)smp * 55;
        int len = 0;
        #pragma unroll 11
        for (int t = 0; t < 55; ++t) len += (op[t] != 18);

        float h[16];
        #pragma unroll
        for (int i = 0; i < 16; ++i) h[i] = 0.f;

        if (len > 0) {
            int o = op[0];
            for (int t = 0; t < len; ++t) {
                int on = (t + 1 < len) ? op[t + 1] : 0;
                float hn[16];
                #pragma unroll 2
                for (int jj = 0; jj < 16; ++jj) {
                    float a = T2[o * 17 + jj];
                    const float4* W4_ = (const float4*)(rw + jj * 16);
                    float4 w0 = W4_[0], w1 = W4_[1], w2 = W4_[2], w3 = W4_[3];
                    float4 h0 = *(const float4*)&h[0],  h1 = *(const float4*)&h[4];
                    float4 h2 = *(const float4*)&h[8],  h3 = *(const float4*)&h[12];
                    FMA16(a, w0,w1,w2,w3, h0,h1,h2,h3);
                    hn[jj] = tanh_(a);
                }
                #pragma unroll
                for (int i = 0; i < 16; ++i) h[i] = hn[i];
                o = on;
            }
        }
        float* hc = ws + OFF_HC + smp * 16;
        #pragma unroll
        for (int i = 0; i < 16; ++i) hc[i] = h[i];
    }
}

// ---------------- k3: fusion MLP (f32 in/out), conditional diagnostic
__global__ void k3_fuse(const float* fW1, const float* fb1,
                        const float* fW2, const float* fb2,
                        float* ws, float* out)
{
    int b = blockIdx.x * 256 + threadIdx.x;
    if (b >= B_) return;
    float inv = 1.f / (ws[OFF_CNT + b] + 1e-8f);
    float comb[48];
    #pragma unroll
    for (int j = 0; j < 16; ++j) comb[j] = ws[OFF_HC + b * 16 + j];
    #pragma unroll
    for (int j = 0; j < 32; ++j) comb[16 + j] = ws[OFF_POOL + b * 32 + j] * inv;

    float hid[16];
    #pragma unroll
    for (int o = 0; o < 16; ++o) {
        float v = fb1[o];
        #pragma unroll
        for (int i = 0; i < 48; ++i) v = fmaf(fW1[o * 48 + i], comb[i], v);
        hid[o] = v > 0.f ? v : 0.f;
    }
    #pragma unroll
    for (int o = 0; o < 24; ++o) {
        float v = fb2[o];
        #pragma unroll
        for (int i = 0; i < 16; ++i) v = fmaf(fW2[o * 16 + i], hid[i], v);
        out[b * 24 + o] = v;
    }

    if (b == 0) {   // silent on success
        int bb = 0;
        if (!badf(ws[OFF_POOL]))    bb |= 1;
        if (!badf(ws[OFF_HC]))      bb |= 2;
        if (ws[OFF_CNT] > 0.5f)     bb |= 4;
        if (bb != 7) {
            float code = 16384.f + 128.f * (float)bb;
            #pragma unroll
            for (int i = 4; i < 12; ++i) out[i] = code;
        }
    }
}

// ------------------------------------------------------------------- launch
extern "C" void kernel_launch(void* const* d_in, const int* in_sizes, int n_in,
                              void* d_out, int out_size, void* d_ws, size_t ws_size,
                              hipStream_t stream)
{
    const int*   oclass = (const int*)d_in[0];
    const int*   strs   = (const int*)d_in[1];
    const float* emb    = (const float*)d_in[2];
    const float* rWih   = (const float*)d_in[3];
    const float* rWhh   = (const float*)d_in[4];
    const float* rbih   = (const float*)d_in[5];
    const float* rbhh   = (const float*)d_in[6];
    const float* gWihF  = (const float*)d_in[7];
    const float* gWhhF  = (const float*)d_in[8];
    const float* gbihF  = (const float*)d_in[9];
    const float* gbhhF  = (const float*)d_in[10];
    const float* gWihB  = (const float*)d_in[11];
    const float* gWhhB  = (const float*)d_in[12];
    const float* gbihB  = (const float*)d_in[13];
    const float* gbhhB  = (const float*)d_in[14];
    const float* fW1    = (const float*)d_in[15];
    const float* fb1    = (const float*)d_in[16];
    const float* fW2    = (const float*)d_in[17];
    const float* fb2    = (const float*)d_in[18];

    float* ws  = (float*)d_ws;
    float* out = (float*)d_out;

    hipMemsetAsync(d_ws, 0, 33792 * sizeof(float), stream);

    k0_tables<<<48, 256, 0, stream>>>(emb, gWihF, gbihF, gbhhF,
                                      gWihB, gbihB, gbhhB, ws);
    k12_main<<<NTOT, 256, 0, stream>>>(oclass, strs, emb,
                                       gWhhF, gbhhF, gWhhB, gbhhB,
                                       rWih, rWhh, rbih, rbhh, ws, out);
    k3_fuse<<<4, 256, 0, stream>>>(fW1, fb1, fW2, fb2, ws, out);
}